// Round 5
// baseline (388.316 us; speedup 1.0000x reference)
//
#include <hip/hip_runtime.h>

#define BB 16
#define TT 256
#define NN 2048
#define TC 8             // t-chunk per block -> grid (2,16,32)=1024 blocks, 4 blocks/CU
#define NSLICE 8         // atomic contention spread (slice = b & 7)
#define WSBASE 16        // scalar slots before per-point arrays

// ws float layout:
//  [0] recon num  [1] temporal num  [2] num_vel  [3] identity sum  [4] num_visible
//  [WSBASE + (s*13 + k)*NN + n], s=0..7, k=0..12: cnt, sp0..2, qp0..2, sg0..2, qg0..2

__device__ __forceinline__ float waveReduceSum(float v) {
#pragma unroll
  for (int o = 32; o > 0; o >>= 1) v += __shfl_down(v, o, 64);
  return v;
}

// Each thread owns 4 consecutive points: per frame it loads 3 float4 (pred),
// 3 float4 (gt), 1 float4 (vis) -- all 16B-aligned, 112 B/lane/frame.
__global__ __launch_bounds__(256) void stats_kernel(
    const float* __restrict__ pred, const float* __restrict__ gt,
    const float* __restrict__ vis, float* __restrict__ ws) {
  const int kg = blockIdx.x * 256 + threadIdx.x;  // point-group index, 0..511
  const int b  = blockIdx.y;
  const int t0 = blockIdx.z * TC;

  const float4* __restrict__ p4 = (const float4*)pred;
  const float4* __restrict__ g4 = (const float4*)gt;
  const float4* __restrict__ v4 = (const float4*)vis;

  const size_t f0 = (size_t)(b * TT + t0);  // first owned frame index
  const size_t kp3 = 3 * (size_t)kg;

  float st[4][13];
#pragma unroll
  for (int p = 0; p < 4; ++p)
#pragma unroll
    for (int k = 0; k < 13; ++k) st[p][k] = 0.f;
  float recon = 0.f, temporal = 0.f, nvel = 0.f;

  // prev-frame state, unpacked: pa/pg = 12 coords each, pm = 4 masks
  float pa[12], pg[12], pm[4];
  {
    const size_t fb = (t0 == 0) ? f0 : f0 - 1;
    const size_t ip = fb * (NN * 3 / 4) + kp3;
    const size_t iv = fb * (NN / 4) + kg;
    float4 A0 = p4[ip], A1 = p4[ip + 1], A2 = p4[ip + 2];
    float4 G0 = g4[ip], G1 = g4[ip + 1], G2 = g4[ip + 2];
    float4 V = v4[iv];
    pa[0]=A0.x; pa[1]=A0.y; pa[2]=A0.z; pa[3]=A0.w; pa[4]=A1.x; pa[5]=A1.y;
    pa[6]=A1.z; pa[7]=A1.w; pa[8]=A2.x; pa[9]=A2.y; pa[10]=A2.z; pa[11]=A2.w;
    pg[0]=G0.x; pg[1]=G0.y; pg[2]=G0.z; pg[3]=G0.w; pg[4]=G1.x; pg[5]=G1.y;
    pg[6]=G1.z; pg[7]=G1.w; pg[8]=G2.x; pg[9]=G2.y; pg[10]=G2.z; pg[11]=G2.w;
    const float z = (t0 == 0) ? 0.f : 1.f;  // first chunk: no t-1 pair
    pm[0] = (V.x > 0.5f) ? z : 0.f;
    pm[1] = (V.y > 0.5f) ? z : 0.f;
    pm[2] = (V.z > 0.5f) ? z : 0.f;
    pm[3] = (V.w > 0.5f) ? z : 0.f;
  }

#pragma unroll
  for (int i = 0; i < TC; ++i) {
    const size_t f = f0 + i;
    const size_t ip = f * (NN * 3 / 4) + kp3;
    const size_t iv = f * (NN / 4) + kg;
    float4 A0 = p4[ip], A1 = p4[ip + 1], A2 = p4[ip + 2];
    float4 G0 = g4[ip], G1 = g4[ip + 1], G2 = g4[ip + 2];
    float4 V = v4[iv];

    float ca[12], cg[12], cm[4];
    ca[0]=A0.x; ca[1]=A0.y; ca[2]=A0.z; ca[3]=A0.w; ca[4]=A1.x; ca[5]=A1.y;
    ca[6]=A1.z; ca[7]=A1.w; ca[8]=A2.x; ca[9]=A2.y; ca[10]=A2.z; ca[11]=A2.w;
    cg[0]=G0.x; cg[1]=G0.y; cg[2]=G0.z; cg[3]=G0.w; cg[4]=G1.x; cg[5]=G1.y;
    cg[6]=G1.z; cg[7]=G1.w; cg[8]=G2.x; cg[9]=G2.y; cg[10]=G2.z; cg[11]=G2.w;
    cm[0] = (V.x > 0.5f) ? 1.f : 0.f;
    cm[1] = (V.y > 0.5f) ? 1.f : 0.f;
    cm[2] = (V.z > 0.5f) ? 1.f : 0.f;
    cm[3] = (V.w > 0.5f) ? 1.f : 0.f;

#pragma unroll
    for (int p = 0; p < 4; ++p) {
      const float m = cm[p];
      const float ax = ca[3*p], ay = ca[3*p+1], az = ca[3*p+2];
      const float gx = cg[3*p], gy = cg[3*p+1], gz = cg[3*p+2];
      st[p][0] += m;
      st[p][1] += m * ax;      st[p][2] += m * ay;      st[p][3] += m * az;
      st[p][4] += m * ax * ax; st[p][5] += m * ay * ay; st[p][6] += m * az * az;
      st[p][7] += m * gx;      st[p][8] += m * gy;      st[p][9] += m * gz;
      st[p][10] += m * gx * gx; st[p][11] += m * gy * gy; st[p][12] += m * gz * gz;
      const float d0 = ax - gx, d1 = ay - gy, d2 = az - gz;
      recon += m * (d0 * d0 + d1 * d1 + 2.f * d2 * d2);

      const float mv = m * pm[p];
      const float vx = (ax - pa[3*p])   - (gx - pg[3*p]);
      const float vy = (ay - pa[3*p+1]) - (gy - pg[3*p+1]);
      const float vz = (az - pa[3*p+2]) - (gz - pg[3*p+2]);
      temporal += mv * (vx * vx + vy * vy + vz * vz);
      nvel += mv;
    }
#pragma unroll
    for (int j = 0; j < 12; ++j) { pa[j] = ca[j]; pg[j] = cg[j]; }
#pragma unroll
    for (int p = 0; p < 4; ++p) pm[p] = cm[p];
  }

  // per-point partials: atomics into NSLICE contention-spread slices
  float* pts = ws + WSBASE + (size_t)(b & (NSLICE - 1)) * 13 * NN;
  const int n0 = kg * 4;
#pragma unroll
  for (int k = 0; k < 13; ++k)
#pragma unroll
    for (int p = 0; p < 4; ++p)
      atomicAdd(&pts[k * NN + n0 + p], st[p][k]);

  // global scalars: block reduce, then one atomic per scalar
  __shared__ float sred[3][4];
  float r0 = waveReduceSum(recon);
  float r1 = waveReduceSum(temporal);
  float r2 = waveReduceSum(nvel);
  int lane = threadIdx.x & 63, w = threadIdx.x >> 6;
  if (lane == 0) { sred[0][w] = r0; sred[1][w] = r1; sred[2][w] = r2; }
  __syncthreads();
  if (threadIdx.x < 3) {
    float s = sred[threadIdx.x][0] + sred[threadIdx.x][1] +
              sred[threadIdx.x][2] + sred[threadIdx.x][3];
    atomicAdd(&ws[threadIdx.x], s);
  }
}

__global__ __launch_bounds__(256) void identity_kernel(float* __restrict__ ws) {
  const int n = blockIdx.x * 256 + threadIdx.x;
  const float* base = ws + WSBASE;
  float st[13];
#pragma unroll
  for (int k = 0; k < 13; ++k) st[k] = 0.f;
#pragma unroll
  for (int s = 0; s < NSLICE; ++s) {
    const float* pts = base + (size_t)s * 13 * NN;
#pragma unroll
    for (int k = 0; k < 13; ++k) st[k] += pts[k * NN + n];
  }
  float c = st[0];
  float sp0 = st[1], sp1 = st[2], sp2 = st[3];
  float qp0 = st[4], qp1 = st[5], qp2 = st[6];
  float sg0 = st[7], sg1 = st[8], sg2 = st[9];
  float qg0 = st[10], qg1 = st[11], qg2 = st[12];

  float inv = 1.f / fmaxf(c, 1.f);        // = 1/c for c>=1; sums are 0 when c==0
  float dv  = 1.f / fmaxf(c - 1.f, 1.f);  // unbiased divisor
  float pv0 = (qp0 - sp0 * sp0 * inv) * dv;
  float pv1 = (qp1 - sp1 * sp1 * inv) * dv;
  float pv2 = (qp2 - sp2 * sp2 * inv) * dv;
  float gv0 = (qg0 - sg0 * sg0 * inv) * dv;
  float gv1 = (qg1 - sg1 * sg1 * inv) * dv;
  float gv2 = (qg2 - sg2 * sg2 * inv) * dv;

  float num = fabsf(pv0 - gv0) + fabsf(pv1 - gv1) + fabsf(pv2 - gv2);
  float den = gv0 + gv1 + gv2 + 1e-6f;
  float contrib = (c > 1.f) ? (num / den) : 0.f;

  __shared__ float sred[2][4];
  float r0 = waveReduceSum(contrib);
  float r1 = waveReduceSum(c);
  int lane = threadIdx.x & 63, w = threadIdx.x >> 6;
  if (lane == 0) { sred[0][w] = r0; sred[1][w] = r1; }
  __syncthreads();
  if (threadIdx.x < 2) {
    float s = sred[threadIdx.x][0] + sred[threadIdx.x][1] +
              sred[threadIdx.x][2] + sred[threadIdx.x][3];
    atomicAdd(&ws[3 + threadIdx.x], s);
  }
}

__global__ void finalize_kernel(const float* __restrict__ ws, float* __restrict__ out) {
  float nv = ws[4];
  float recon = (nv > 0.f) ? ws[0] / fmaxf(nv, 1.f) : 0.f;
  float nvel = ws[2];
  float temporal = (nvel > 0.f) ? ws[1] / fmaxf(nvel, 1.f) : 0.f;
  float identity = ws[3] / (float)NN;

  float rl = recon, tl = temporal, il = identity;
  bool all_pos = (rl > 0.f) && (tl > 0.f) && (il > 0.f);
  float maxc = fmaxf(rl, fmaxf(tl, il));
  float target = maxc / 3.f;
  float thresh = 10.f * target;
  float rw = (all_pos && rl > thresh) ? 1.0f * target / fmaxf(rl, 1e-30f) : 1.0f;
  float tw = (all_pos && tl > thresh) ? 0.5f * target / fmaxf(tl, 1e-30f) : 0.5f;
  float iw = (all_pos && il > thresh) ? 0.1f * target / fmaxf(il, 1e-30f) : 0.1f;

  out[0] = rw * recon + tw * temporal + iw * identity;
  out[1] = recon;
  out[2] = temporal;
  out[3] = identity;
}

extern "C" void kernel_launch(void* const* d_in, const int* in_sizes, int n_in,
                              void* d_out, int out_size, void* d_ws, size_t ws_size,
                              hipStream_t stream) {
  const float* pred = (const float*)d_in[0];
  const float* gt   = (const float*)d_in[1];
  const float* vis  = (const float*)d_in[2];
  float* out = (float*)d_out;
  float* ws  = (float*)d_ws;

  hipMemsetAsync(d_ws, 0, (WSBASE + (size_t)NSLICE * 13 * NN) * sizeof(float), stream);

  dim3 g1(NN / 1024, BB, TT / TC);  // (2, 16, 32) = 1024 blocks
  stats_kernel<<<g1, 256, 0, stream>>>(pred, gt, vis, ws);
  identity_kernel<<<dim3(NN / 256), 256, 0, stream>>>(ws);
  finalize_kernel<<<1, 1, 0, stream>>>(ws, out);
}

// Round 6
// 294.994 us; speedup vs baseline: 1.3163x; 1.3163x over previous
//
#include <hip/hip_runtime.h>

#define BB 16
#define TT 256
#define NN 2048
#define TC 16            // frames per block -> grid (1,16,16)=256 blocks, 1024 thr
#define NSLICE 8         // atomic contention spread
#define WSBASE 16        // scalar slots before per-point arrays

// ws float layout:
//  [0] recon num  [1] temporal num  [2] num_vel  [3] identity sum  [4] num_visible
//  [WSBASE + (s*13 + k)*NN + n], s=0..7, k=0..12: cnt, sp0..2, qp0..2, sg0..2, qg0..2

__device__ __forceinline__ float waveReduceSum(float v) {
#pragma unroll
  for (int o = 32; o > 0; o >>= 1) v += __shfl_down(v, o, 64);
  return v;
}

// Block = 1024 threads covers the FULL frame (thread i owns points 2i, 2i+1).
// The block walks t sequentially, so its three streams (pred, gt, vis) are
// each fully contiguous in memory -- copy-kernel-like DRAM row locality.
__global__ __launch_bounds__(1024) void stats_kernel(
    const float* __restrict__ pred, const float* __restrict__ gt,
    const float* __restrict__ vis, float* __restrict__ ws) {
  const int i  = threadIdx.x;          // 0..1023
  const int b  = blockIdx.y;
  const int tz = blockIdx.z;
  const int t0 = tz * TC;

  const float2* __restrict__ p2 = (const float2*)pred;
  const float2* __restrict__ g2 = (const float2*)gt;
  const float2* __restrict__ v2 = (const float2*)vis;

  // frame f: pred/gt float2 index = f*3072 + 3i ; vis float2 index = f*1024 + i
  const size_t f0 = (size_t)(b * TT + t0);
  const size_t i3 = 3 * (size_t)i;

  float st0[13], st1[13];
#pragma unroll
  for (int k = 0; k < 13; ++k) { st0[k] = 0.f; st1[k] = 0.f; }
  float recon = 0.f, temporal = 0.f, nvel = 0.f;

  // prev-frame state: 2 points x (3 pred + 3 gt) + 2 masks
  float pa0, pa1, pa2, pb0, pb1, pb2;   // pred pt0, pt1
  float qa0, qa1, qa2, qb0, qb1, qb2;   // gt   pt0, pt1
  float pm0, pm1;
  {
    const size_t fb = (t0 == 0) ? f0 : f0 - 1;
    float2 A0 = p2[fb * 3072 + i3], A1 = p2[fb * 3072 + i3 + 1], A2 = p2[fb * 3072 + i3 + 2];
    float2 G0 = g2[fb * 3072 + i3], G1 = g2[fb * 3072 + i3 + 1], G2 = g2[fb * 3072 + i3 + 2];
    float2 V  = v2[fb * 1024 + i];
    pa0 = A0.x; pa1 = A0.y; pa2 = A1.x;  pb0 = A1.y; pb1 = A2.x; pb2 = A2.y;
    qa0 = G0.x; qa1 = G0.y; qa2 = G1.x;  qb0 = G1.y; qb1 = G2.x; qb2 = G2.y;
    const float z = (t0 == 0) ? 0.f : 1.f;  // first chunk: no t-1 pair
    pm0 = (V.x > 0.5f) ? z : 0.f;
    pm1 = (V.y > 0.5f) ? z : 0.f;
  }

#pragma unroll
  for (int t = 0; t < TC; ++t) {
    const size_t f = f0 + t;
    float2 A0 = p2[f * 3072 + i3], A1 = p2[f * 3072 + i3 + 1], A2 = p2[f * 3072 + i3 + 2];
    float2 G0 = g2[f * 3072 + i3], G1 = g2[f * 3072 + i3 + 1], G2 = g2[f * 3072 + i3 + 2];
    float2 V  = v2[f * 1024 + i];

    const float a00 = A0.x, a01 = A0.y, a02 = A1.x;   // point 2i
    const float a10 = A1.y, a11 = A2.x, a12 = A2.y;   // point 2i+1
    const float g00 = G0.x, g01 = G0.y, g02 = G1.x;
    const float g10 = G1.y, g11 = G2.x, g12 = G2.y;
    const float m0 = (V.x > 0.5f) ? 1.f : 0.f;
    const float m1 = (V.y > 0.5f) ? 1.f : 0.f;

    // --- point 0 ---
    st0[0] += m0;
    st0[1] += m0 * a00;       st0[2] += m0 * a01;       st0[3] += m0 * a02;
    st0[4] += m0 * a00 * a00; st0[5] += m0 * a01 * a01; st0[6] += m0 * a02 * a02;
    st0[7] += m0 * g00;       st0[8] += m0 * g01;       st0[9] += m0 * g02;
    st0[10] += m0 * g00 * g00; st0[11] += m0 * g01 * g01; st0[12] += m0 * g02 * g02;
    {
      const float d0 = a00 - g00, d1 = a01 - g01, d2 = a02 - g02;
      recon += m0 * (d0 * d0 + d1 * d1 + 2.f * d2 * d2);
      const float mv = m0 * pm0;
      const float vx = (a00 - pa0) - (g00 - qa0);
      const float vy = (a01 - pa1) - (g01 - qa1);
      const float vz = (a02 - pa2) - (g02 - qa2);
      temporal += mv * (vx * vx + vy * vy + vz * vz);
      nvel += mv;
    }
    // --- point 1 ---
    st1[0] += m1;
    st1[1] += m1 * a10;       st1[2] += m1 * a11;       st1[3] += m1 * a12;
    st1[4] += m1 * a10 * a10; st1[5] += m1 * a11 * a11; st1[6] += m1 * a12 * a12;
    st1[7] += m1 * g10;       st1[8] += m1 * g11;       st1[9] += m1 * g12;
    st1[10] += m1 * g10 * g10; st1[11] += m1 * g11 * g11; st1[12] += m1 * g12 * g12;
    {
      const float d0 = a10 - g10, d1 = a11 - g11, d2 = a12 - g12;
      recon += m1 * (d0 * d0 + d1 * d1 + 2.f * d2 * d2);
      const float mv = m1 * pm1;
      const float vx = (a10 - pb0) - (g10 - qb0);
      const float vy = (a11 - pb1) - (g11 - qb1);
      const float vz = (a12 - pb2) - (g12 - qb2);
      temporal += mv * (vx * vx + vy * vy + vz * vz);
      nvel += mv;
    }

    pa0 = a00; pa1 = a01; pa2 = a02; pb0 = a10; pb1 = a11; pb2 = a12;
    qa0 = g00; qa1 = g01; qa2 = g02; qb0 = g10; qb1 = g11; qb2 = g12;
    pm0 = m0; pm1 = m1;
  }

  // per-point partials: single-address atomics (R3-proven cheap pattern)
  float* pts = ws + WSBASE + (size_t)((b * (TT / TC) + tz) & (NSLICE - 1)) * 13 * NN;
  const int n0 = 2 * i;
#pragma unroll
  for (int k = 0; k < 13; ++k) atomicAdd(&pts[k * NN + n0], st0[k]);
#pragma unroll
  for (int k = 0; k < 13; ++k) atomicAdd(&pts[k * NN + n0 + 1], st1[k]);

  // global scalars: block reduce over 16 waves, then one atomic per scalar
  __shared__ float sred[3][16];
  float r0 = waveReduceSum(recon);
  float r1 = waveReduceSum(temporal);
  float r2 = waveReduceSum(nvel);
  int lane = threadIdx.x & 63, w = threadIdx.x >> 6;
  if (lane == 0) { sred[0][w] = r0; sred[1][w] = r1; sred[2][w] = r2; }
  __syncthreads();
  if (threadIdx.x < 3) {
    float s = 0.f;
#pragma unroll
    for (int j = 0; j < 16; ++j) s += sred[threadIdx.x][j];
    atomicAdd(&ws[threadIdx.x], s);
  }
}

__global__ __launch_bounds__(256) void identity_kernel(float* __restrict__ ws) {
  const int n = blockIdx.x * 256 + threadIdx.x;
  const float* base = ws + WSBASE;
  float st[13];
#pragma unroll
  for (int k = 0; k < 13; ++k) st[k] = 0.f;
#pragma unroll
  for (int s = 0; s < NSLICE; ++s) {
    const float* pts = base + (size_t)s * 13 * NN;
#pragma unroll
    for (int k = 0; k < 13; ++k) st[k] += pts[k * NN + n];
  }
  float c = st[0];
  float sp0 = st[1], sp1 = st[2], sp2 = st[3];
  float qp0 = st[4], qp1 = st[5], qp2 = st[6];
  float sg0 = st[7], sg1 = st[8], sg2 = st[9];
  float qg0 = st[10], qg1 = st[11], qg2 = st[12];

  float inv = 1.f / fmaxf(c, 1.f);        // = 1/c for c>=1; sums are 0 when c==0
  float dv  = 1.f / fmaxf(c - 1.f, 1.f);  // unbiased divisor
  float pv0 = (qp0 - sp0 * sp0 * inv) * dv;
  float pv1 = (qp1 - sp1 * sp1 * inv) * dv;
  float pv2 = (qp2 - sp2 * sp2 * inv) * dv;
  float gv0 = (qg0 - sg0 * sg0 * inv) * dv;
  float gv1 = (qg1 - sg1 * sg1 * inv) * dv;
  float gv2 = (qg2 - sg2 * sg2 * inv) * dv;

  float num = fabsf(pv0 - gv0) + fabsf(pv1 - gv1) + fabsf(pv2 - gv2);
  float den = gv0 + gv1 + gv2 + 1e-6f;
  float contrib = (c > 1.f) ? (num / den) : 0.f;

  __shared__ float sred[2][4];
  float r0 = waveReduceSum(contrib);
  float r1 = waveReduceSum(c);
  int lane = threadIdx.x & 63, w = threadIdx.x >> 6;
  if (lane == 0) { sred[0][w] = r0; sred[1][w] = r1; }
  __syncthreads();
  if (threadIdx.x < 2) {
    float s = sred[threadIdx.x][0] + sred[threadIdx.x][1] +
              sred[threadIdx.x][2] + sred[threadIdx.x][3];
    atomicAdd(&ws[3 + threadIdx.x], s);
  }
}

__global__ void finalize_kernel(const float* __restrict__ ws, float* __restrict__ out) {
  float nv = ws[4];
  float recon = (nv > 0.f) ? ws[0] / fmaxf(nv, 1.f) : 0.f;
  float nvel = ws[2];
  float temporal = (nvel > 0.f) ? ws[1] / fmaxf(nvel, 1.f) : 0.f;
  float identity = ws[3] / (float)NN;

  float rl = recon, tl = temporal, il = identity;
  bool all_pos = (rl > 0.f) && (tl > 0.f) && (il > 0.f);
  float maxc = fmaxf(rl, fmaxf(tl, il));
  float target = maxc / 3.f;
  float thresh = 10.f * target;
  float rw = (all_pos && rl > thresh) ? 1.0f * target / fmaxf(rl, 1e-30f) : 1.0f;
  float tw = (all_pos && tl > thresh) ? 0.5f * target / fmaxf(tl, 1e-30f) : 0.5f;
  float iw = (all_pos && il > thresh) ? 0.1f * target / fmaxf(il, 1e-30f) : 0.1f;

  out[0] = rw * recon + tw * temporal + iw * identity;
  out[1] = recon;
  out[2] = temporal;
  out[3] = identity;
}

extern "C" void kernel_launch(void* const* d_in, const int* in_sizes, int n_in,
                              void* d_out, int out_size, void* d_ws, size_t ws_size,
                              hipStream_t stream) {
  const float* pred = (const float*)d_in[0];
  const float* gt   = (const float*)d_in[1];
  const float* vis  = (const float*)d_in[2];
  float* out = (float*)d_out;
  float* ws  = (float*)d_ws;

  hipMemsetAsync(d_ws, 0, (WSBASE + (size_t)NSLICE * 13 * NN) * sizeof(float), stream);

  dim3 g1(1, BB, TT / TC);  // (1, 16, 16) = 256 blocks of 1024 threads
  stats_kernel<<<g1, 1024, 0, stream>>>(pred, gt, vis, ws);
  identity_kernel<<<dim3(NN / 256), 256, 0, stream>>>(ws);
  finalize_kernel<<<1, 1, 0, stream>>>(ws, out);
}

// Round 7
// 268.187 us; speedup vs baseline: 1.4479x; 1.1000x over previous
//
#include <hip/hip_runtime.h>
#include <stdint.h>

#define BB 16
#define TT 256
#define NN 2048
#define TC 16            // frames per block
#define NSLICE 8         // atomic contention spread
#define WSBASE 16        // scalar slots before per-point arrays

// staging geometry: slab = 1024 points, frame tile = pred 12KB + gt 12KB + vis 4KB
#define SLAB 1024
#define F4_PER_BUF 1792          // 28672 B / 16
#define GT_F4 768                // gt region starts at float4 index 768
#define VIS_F4 1536              // vis region starts at float4 index 1536

// ws float layout:
//  [0] recon num  [1] temporal num  [2] num_vel  [3] identity sum  [4] num_visible
//  [WSBASE + (s*13 + k)*NN + n], s=0..7, k=0..12: cnt, sp0..2, qp0..2, sg0..2, qg0..2

__device__ __forceinline__ float waveReduceSum(float v) {
#pragma unroll
  for (int o = 32; o > 0; o >>= 1) v += __shfl_down(v, o, 64);
  return v;
}

#define GLDS16(g, l)                                               \
  __builtin_amdgcn_global_load_lds(                                \
      (const __attribute__((address_space(1))) void*)(g),          \
      (__attribute__((address_space(3))) void*)(l), 16, 0, 0)

__global__ __launch_bounds__(256) void stats_kernel(
    const float* __restrict__ pred, const float* __restrict__ gt,
    const float* __restrict__ vis, float* __restrict__ ws) {
  const int tid  = threadIdx.x;
  const int lane = tid & 63;
  const int w    = tid >> 6;          // wave 0..3
  const int xs   = blockIdx.x;        // slab 0/1
  const int b    = blockIdx.y;
  const int tz   = blockIdx.z;
  const int t0   = tz * TC;

  __shared__ union {
    float4 stage[2][F4_PER_BUF];      // 2 x 28672 B
    float  xp[13 * SLAB];             // 53248 B transpose area (reused)
  } sm;
  __shared__ float sred[3][4];

  const char* predB = (const char*)pred;
  const char* gtB   = (const char*)gt;
  const char* visB  = (const char*)vis;

  // stage one frame (28 x 1KB chunks); wave w owns chunks [7w, 7w+7)
  auto stage_frame = [&](int buf, int f) {
    const size_t pfb = (size_t)f * 24576 + (size_t)xs * 12288;  // pred/gt slab base
    const size_t vfb = (size_t)f * 8192 + (size_t)xs * 4096;    // vis slab base
    char* lbase = (char*)&sm.stage[buf][0];
#pragma unroll
    for (int j = 0; j < 7; ++j) {
      const int c = w * 7 + j;                 // wave-uniform chunk id
      const char* g;
      char* l;
      if (c < 12) {
        g = predB + pfb + (size_t)c * 1024;
        l = lbase + c * 1024;
      } else if (c < 24) {
        g = gtB + pfb + (size_t)(c - 12) * 1024;
        l = lbase + 12288 + (c - 12) * 1024;
      } else {
        g = visB + vfb + (size_t)(c - 24) * 1024;
        l = lbase + 24576 + (c - 24) * 1024;
      }
      GLDS16(g + (size_t)lane * 16, l);
    }
  };

  // accumulators
  float st[4][13];
#pragma unroll
  for (int p = 0; p < 4; ++p)
#pragma unroll
    for (int k = 0; k < 13; ++k) st[p][k] = 0.f;
  float recon = 0.f, temporal = 0.f, nvel = 0.f;

  // boundary prev-frame -> registers (tiny; direct global float4 loads)
  float pa[12], pg[12], pm[4];
  {
    const int fb = (t0 == 0) ? (b * TT) : (b * TT + t0 - 1);
    const float4* pf = (const float4*)(predB + (size_t)fb * 24576 + (size_t)xs * 12288);
    const float4* gf = (const float4*)(gtB + (size_t)fb * 24576 + (size_t)xs * 12288);
    const float4* vf = (const float4*)(visB + (size_t)fb * 8192 + (size_t)xs * 4096);
    float4 A0 = pf[tid * 3], A1 = pf[tid * 3 + 1], A2 = pf[tid * 3 + 2];
    float4 G0 = gf[tid * 3], G1 = gf[tid * 3 + 1], G2 = gf[tid * 3 + 2];
    float4 V = vf[tid];
    pa[0]=A0.x; pa[1]=A0.y; pa[2]=A0.z; pa[3]=A0.w; pa[4]=A1.x; pa[5]=A1.y;
    pa[6]=A1.z; pa[7]=A1.w; pa[8]=A2.x; pa[9]=A2.y; pa[10]=A2.z; pa[11]=A2.w;
    pg[0]=G0.x; pg[1]=G0.y; pg[2]=G0.z; pg[3]=G0.w; pg[4]=G1.x; pg[5]=G1.y;
    pg[6]=G1.z; pg[7]=G1.w; pg[8]=G2.x; pg[9]=G2.y; pg[10]=G2.z; pg[11]=G2.w;
    const float z = (t0 == 0) ? 0.f : 1.f;   // first chunk: no t-1 pair
    pm[0] = (V.x > 0.5f) ? z : 0.f;
    pm[1] = (V.y > 0.5f) ? z : 0.f;
    pm[2] = (V.z > 0.5f) ? z : 0.f;
    pm[3] = (V.w > 0.5f) ? z : 0.f;
  }

  stage_frame(0, b * TT + t0);
  __syncthreads();   // drains wave's own global_load_lds (vmcnt) + barrier

  for (int t = 0; t < TC; ++t) {
    if (t + 1 < TC) stage_frame((t + 1) & 1, b * TT + t0 + t + 1);  // async fire

    const float4* s4 = &sm.stage[t & 1][0];
    float4 A0 = s4[tid * 3], A1 = s4[tid * 3 + 1], A2 = s4[tid * 3 + 2];
    float4 G0 = s4[GT_F4 + tid * 3], G1 = s4[GT_F4 + tid * 3 + 1], G2 = s4[GT_F4 + tid * 3 + 2];
    float4 V = s4[VIS_F4 + tid];

    float ca[12], cg[12], cm[4];
    ca[0]=A0.x; ca[1]=A0.y; ca[2]=A0.z; ca[3]=A0.w; ca[4]=A1.x; ca[5]=A1.y;
    ca[6]=A1.z; ca[7]=A1.w; ca[8]=A2.x; ca[9]=A2.y; ca[10]=A2.z; ca[11]=A2.w;
    cg[0]=G0.x; cg[1]=G0.y; cg[2]=G0.z; cg[3]=G0.w; cg[4]=G1.x; cg[5]=G1.y;
    cg[6]=G1.z; cg[7]=G1.w; cg[8]=G2.x; cg[9]=G2.y; cg[10]=G2.z; cg[11]=G2.w;
    cm[0] = (V.x > 0.5f) ? 1.f : 0.f;
    cm[1] = (V.y > 0.5f) ? 1.f : 0.f;
    cm[2] = (V.z > 0.5f) ? 1.f : 0.f;
    cm[3] = (V.w > 0.5f) ? 1.f : 0.f;

#pragma unroll
    for (int p = 0; p < 4; ++p) {
      const float m = cm[p];
      const float ax = ca[3*p], ay = ca[3*p+1], az = ca[3*p+2];
      const float gx = cg[3*p], gy = cg[3*p+1], gz = cg[3*p+2];
      st[p][0] += m;
      st[p][1] += m * ax;       st[p][2] += m * ay;       st[p][3] += m * az;
      st[p][4] += m * ax * ax;  st[p][5] += m * ay * ay;  st[p][6] += m * az * az;
      st[p][7] += m * gx;       st[p][8] += m * gy;       st[p][9] += m * gz;
      st[p][10] += m * gx * gx; st[p][11] += m * gy * gy; st[p][12] += m * gz * gz;
      const float d0 = ax - gx, d1 = ay - gy, d2 = az - gz;
      recon += m * (d0 * d0 + d1 * d1 + 2.f * d2 * d2);

      const float mv = m * pm[p];
      const float vx = (ax - pa[3*p])   - (gx - pg[3*p]);
      const float vy = (ay - pa[3*p+1]) - (gy - pg[3*p+1]);
      const float vz = (az - pa[3*p+2]) - (gz - pg[3*p+2]);
      temporal += mv * (vx * vx + vy * vy + vz * vz);
      nvel += mv;
    }
#pragma unroll
    for (int j = 0; j < 12; ++j) { pa[j] = ca[j]; pg[j] = cg[j]; }
#pragma unroll
    for (int p = 0; p < 4; ++p) pm[p] = cm[p];

    __syncthreads();  // (a) next buffer staged, (b) safe to overwrite cur next iter
  }

  // transpose per-point stats through LDS so atomic addresses are lane-contiguous
#pragma unroll
  for (int k = 0; k < 13; ++k)
#pragma unroll
    for (int p = 0; p < 4; ++p)
      sm.xp[k * SLAB + tid * 4 + p] = st[p][k];
  __syncthreads();

  float* pts = ws + WSBASE +
               (size_t)((b * (TT / TC) + tz) & (NSLICE - 1)) * 13 * NN;
  const int nb = xs * SLAB;
#pragma unroll
  for (int k = 0; k < 13; ++k)
#pragma unroll
    for (int j = 0; j < 4; ++j)
      atomicAdd(&pts[k * NN + nb + j * 256 + tid],
                sm.xp[k * SLAB + j * 256 + tid]);

  // global scalars: block reduce, then one atomic per scalar
  float r0 = waveReduceSum(recon);
  float r1 = waveReduceSum(temporal);
  float r2 = waveReduceSum(nvel);
  if (lane == 0) { sred[0][w] = r0; sred[1][w] = r1; sred[2][w] = r2; }
  __syncthreads();
  if (tid < 3) {
    float s = sred[tid][0] + sred[tid][1] + sred[tid][2] + sred[tid][3];
    atomicAdd(&ws[tid], s);
  }
}

__global__ __launch_bounds__(256) void identity_kernel(float* __restrict__ ws) {
  const int n = blockIdx.x * 256 + threadIdx.x;
  const float* base = ws + WSBASE;
  float st[13];
#pragma unroll
  for (int k = 0; k < 13; ++k) st[k] = 0.f;
#pragma unroll
  for (int s = 0; s < NSLICE; ++s) {
    const float* pts = base + (size_t)s * 13 * NN;
#pragma unroll
    for (int k = 0; k < 13; ++k) st[k] += pts[k * NN + n];
  }
  float c = st[0];
  float sp0 = st[1], sp1 = st[2], sp2 = st[3];
  float qp0 = st[4], qp1 = st[5], qp2 = st[6];
  float sg0 = st[7], sg1 = st[8], sg2 = st[9];
  float qg0 = st[10], qg1 = st[11], qg2 = st[12];

  float inv = 1.f / fmaxf(c, 1.f);
  float dv  = 1.f / fmaxf(c - 1.f, 1.f);
  float pv0 = (qp0 - sp0 * sp0 * inv) * dv;
  float pv1 = (qp1 - sp1 * sp1 * inv) * dv;
  float pv2 = (qp2 - sp2 * sp2 * inv) * dv;
  float gv0 = (qg0 - sg0 * sg0 * inv) * dv;
  float gv1 = (qg1 - sg1 * sg1 * inv) * dv;
  float gv2 = (qg2 - sg2 * sg2 * inv) * dv;

  float num = fabsf(pv0 - gv0) + fabsf(pv1 - gv1) + fabsf(pv2 - gv2);
  float den = gv0 + gv1 + gv2 + 1e-6f;
  float contrib = (c > 1.f) ? (num / den) : 0.f;

  __shared__ float sred[2][4];
  float r0 = waveReduceSum(contrib);
  float r1 = waveReduceSum(c);
  int lane = threadIdx.x & 63, w = threadIdx.x >> 6;
  if (lane == 0) { sred[0][w] = r0; sred[1][w] = r1; }
  __syncthreads();
  if (threadIdx.x < 2) {
    float s = sred[threadIdx.x][0] + sred[threadIdx.x][1] +
              sred[threadIdx.x][2] + sred[threadIdx.x][3];
    atomicAdd(&ws[3 + threadIdx.x], s);
  }
}

__global__ void finalize_kernel(const float* __restrict__ ws, float* __restrict__ out) {
  float nv = ws[4];
  float recon = (nv > 0.f) ? ws[0] / fmaxf(nv, 1.f) : 0.f;
  float nvel = ws[2];
  float temporal = (nvel > 0.f) ? ws[1] / fmaxf(nvel, 1.f) : 0.f;
  float identity = ws[3] / (float)NN;

  float rl = recon, tl = temporal, il = identity;
  bool all_pos = (rl > 0.f) && (tl > 0.f) && (il > 0.f);
  float maxc = fmaxf(rl, fmaxf(tl, il));
  float target = maxc / 3.f;
  float thresh = 10.f * target;
  float rw = (all_pos && rl > thresh) ? 1.0f * target / fmaxf(rl, 1e-30f) : 1.0f;
  float tw = (all_pos && tl > thresh) ? 0.5f * target / fmaxf(tl, 1e-30f) : 0.5f;
  float iw = (all_pos && il > thresh) ? 0.1f * target / fmaxf(il, 1e-30f) : 0.1f;

  out[0] = rw * recon + tw * temporal + iw * identity;
  out[1] = recon;
  out[2] = temporal;
  out[3] = identity;
}

extern "C" void kernel_launch(void* const* d_in, const int* in_sizes, int n_in,
                              void* d_out, int out_size, void* d_ws, size_t ws_size,
                              hipStream_t stream) {
  const float* pred = (const float*)d_in[0];
  const float* gt   = (const float*)d_in[1];
  const float* vis  = (const float*)d_in[2];
  float* out = (float*)d_out;
  float* ws  = (float*)d_ws;

  hipMemsetAsync(d_ws, 0, (WSBASE + (size_t)NSLICE * 13 * NN) * sizeof(float), stream);

  dim3 g1(NN / SLAB, BB, TT / TC);  // (2, 16, 16) = 512 blocks, 2/CU
  stats_kernel<<<g1, 256, 0, stream>>>(pred, gt, vis, ws);
  identity_kernel<<<dim3(NN / 256), 256, 0, stream>>>(ws);
  finalize_kernel<<<1, 1, 0, stream>>>(ws, out);
}

// Round 8
// 260.806 us; speedup vs baseline: 1.4889x; 1.0283x over previous
//
#include <hip/hip_runtime.h>

#define BB 16
#define TT 256
#define NN 2048
#define TC 16            // t-chunk per block (2048 blocks -> 8 blocks/CU)
#define NSLICE 8         // atomic contention spread (slice = b & 7)
#define WSBASE 16        // scalar slots before per-point arrays

// ws float layout:
//  [0] recon num  [1] temporal num  [2] num_vel
//  [WSBASE + (s*13 + k)*NN + n], s=0..7, k=0..12: cnt, sp0..2, qp0..2, sg0..2, qg0..2

__device__ __forceinline__ float waveReduceSum(float v) {
#pragma unroll
  for (int o = 32; o > 0; o >>= 1) v += __shfl_down(v, o, 64);
  return v;
}

__device__ __forceinline__ float ldnt(const float* p) {
  return __builtin_nontemporal_load(p);
}

__global__ __launch_bounds__(256, 8) void stats_kernel(
    const float* __restrict__ pred, const float* __restrict__ gt,
    const float* __restrict__ vis, float* __restrict__ ws) {
  const int n  = blockIdx.x * 256 + threadIdx.x;
  const int b  = blockIdx.y;
  const int t0 = blockIdx.z * TC;

  const size_t frame0 = (size_t)(b * TT + t0) * NN + n;
  const float* __restrict__ pp = pred + frame0 * 3;
  const float* __restrict__ gp = gt + frame0 * 3;
  const float* __restrict__ vp = vis + frame0;

  float cnt = 0.f;
  float sp0 = 0, sp1 = 0, sp2 = 0, qp0 = 0, qp1 = 0, qp2 = 0;
  float sg0 = 0, sg1 = 0, sg2 = 0, qg0 = 0, qg1 = 0, qg2 = 0;
  float recon = 0, temporal = 0, nvel = 0;

  // boundary frame t0-1 (velocity only). For t0==0 load frame 0 with mask 0.
  float pa0, pa1, pa2, pg0v, pg1v, pg2v, mprev;
  {
    const long off = (t0 == 0) ? 0 : -(long)NN;
    pa0 = ldnt(pp + off * 3);     pa1 = ldnt(pp + off * 3 + 1); pa2 = ldnt(pp + off * 3 + 2);
    pg0v = ldnt(gp + off * 3);    pg1v = ldnt(gp + off * 3 + 1); pg2v = ldnt(gp + off * 3 + 2);
    float v = ldnt(vp + off);
    mprev = (t0 != 0 && v > 0.5f) ? 1.f : 0.f;
  }

#pragma unroll
  for (int i = 0; i < TC; ++i) {
    const size_t e3 = (size_t)i * NN * 3;
    float ax = ldnt(pp + e3), ay = ldnt(pp + e3 + 1), az = ldnt(pp + e3 + 2);
    float gx = ldnt(gp + e3), gy = ldnt(gp + e3 + 1), gz = ldnt(gp + e3 + 2);
    float v = ldnt(vp + (size_t)i * NN);
    float m = (v > 0.5f) ? 1.f : 0.f;

    cnt += m;
    sp0 += m * ax;      sp1 += m * ay;      sp2 += m * az;
    qp0 += m * ax * ax; qp1 += m * ay * ay; qp2 += m * az * az;
    sg0 += m * gx;      sg1 += m * gy;      sg2 += m * gz;
    qg0 += m * gx * gx; qg1 += m * gy * gy; qg2 += m * gz * gz;
    float d0 = ax - gx, d1 = ay - gy, d2 = az - gz;
    recon += m * (d0 * d0 + d1 * d1 + 2.f * d2 * d2);

    float mv = m * mprev;
    float vx = (ax - pa0) - (gx - pg0v);
    float vy = (ay - pa1) - (gy - pg1v);
    float vz = (az - pa2) - (gz - pg2v);
    temporal += mv * (vx * vx + vy * vy + vz * vz);
    nvel += mv;

    pa0 = ax; pa1 = ay; pa2 = az; pg0v = gx; pg1v = gy; pg2v = gz; mprev = m;
  }

  // per-point partials: atomics into NSLICE contention-spread slices (R3-proven)
  float st[13] = {cnt, sp0, sp1, sp2, qp0, qp1, qp2,
                  sg0, sg1, sg2, qg0, qg1, qg2};
  float* pts = ws + WSBASE + (size_t)(b & (NSLICE - 1)) * 13 * NN;
#pragma unroll
  for (int k = 0; k < 13; ++k) atomicAdd(&pts[k * NN + n], st[k]);

  // global scalars: block reduce, then one atomic per scalar
  __shared__ float sred[3][4];
  float r0 = waveReduceSum(recon);
  float r1 = waveReduceSum(temporal);
  float r2 = waveReduceSum(nvel);
  int lane = threadIdx.x & 63, w = threadIdx.x >> 6;
  if (lane == 0) { sred[0][w] = r0; sred[1][w] = r1; sred[2][w] = r2; }
  __syncthreads();
  if (threadIdx.x < 3) {
    float s = sred[threadIdx.x][0] + sred[threadIdx.x][1] +
              sred[threadIdx.x][2] + sred[threadIdx.x][3];
    atomicAdd(&ws[threadIdx.x], s);
  }
}

// Fused identity + finalize: single block of 1024 threads, each owns 2 points.
__global__ __launch_bounds__(1024) void final_kernel(float* __restrict__ ws,
                                                     float* __restrict__ out) {
  const float* base = ws + WSBASE;
  float csum = 0.f, contrib = 0.f;

#pragma unroll
  for (int rep = 0; rep < 2; ++rep) {
    const int n = threadIdx.x + rep * 1024;
    float st[13];
#pragma unroll
    for (int k = 0; k < 13; ++k) st[k] = 0.f;
#pragma unroll
    for (int s = 0; s < NSLICE; ++s) {
      const float* pts = base + (size_t)s * 13 * NN;
#pragma unroll
      for (int k = 0; k < 13; ++k) st[k] += pts[k * NN + n];
    }
    float c = st[0];
    float inv = 1.f / fmaxf(c, 1.f);
    float dv  = 1.f / fmaxf(c - 1.f, 1.f);
    float pv0 = (st[4] - st[1] * st[1] * inv) * dv;
    float pv1 = (st[5] - st[2] * st[2] * inv) * dv;
    float pv2 = (st[6] - st[3] * st[3] * inv) * dv;
    float gv0 = (st[10] - st[7] * st[7] * inv) * dv;
    float gv1 = (st[11] - st[8] * st[8] * inv) * dv;
    float gv2 = (st[12] - st[9] * st[9] * inv) * dv;
    float num = fabsf(pv0 - gv0) + fabsf(pv1 - gv1) + fabsf(pv2 - gv2);
    float den = gv0 + gv1 + gv2 + 1e-6f;
    contrib += (c > 1.f) ? (num / den) : 0.f;
    csum += c;
  }

  __shared__ float sred[2][16];
  float r0 = waveReduceSum(contrib);
  float r1 = waveReduceSum(csum);
  int lane = threadIdx.x & 63, w = threadIdx.x >> 6;
  if (lane == 0) { sred[0][w] = r0; sred[1][w] = r1; }
  __syncthreads();

  if (threadIdx.x == 0) {
    float idsum = 0.f, nv = 0.f;
#pragma unroll
    for (int j = 0; j < 16; ++j) { idsum += sred[0][j]; nv += sred[1][j]; }

    float recon = (nv > 0.f) ? ws[0] / fmaxf(nv, 1.f) : 0.f;
    float nvel = ws[2];
    float temporal = (nvel > 0.f) ? ws[1] / fmaxf(nvel, 1.f) : 0.f;
    float identity = idsum / (float)NN;

    float rl = recon, tl = temporal, il = identity;
    bool all_pos = (rl > 0.f) && (tl > 0.f) && (il > 0.f);
    float maxc = fmaxf(rl, fmaxf(tl, il));
    float target = maxc / 3.f;
    float thresh = 10.f * target;
    float rw = (all_pos && rl > thresh) ? 1.0f * target / fmaxf(rl, 1e-30f) : 1.0f;
    float tw = (all_pos && tl > thresh) ? 0.5f * target / fmaxf(tl, 1e-30f) : 0.5f;
    float iw = (all_pos && il > thresh) ? 0.1f * target / fmaxf(il, 1e-30f) : 0.1f;

    out[0] = rw * recon + tw * temporal + iw * identity;
    out[1] = recon;
    out[2] = temporal;
    out[3] = identity;
  }
}

extern "C" void kernel_launch(void* const* d_in, const int* in_sizes, int n_in,
                              void* d_out, int out_size, void* d_ws, size_t ws_size,
                              hipStream_t stream) {
  const float* pred = (const float*)d_in[0];
  const float* gt   = (const float*)d_in[1];
  const float* vis  = (const float*)d_in[2];
  float* out = (float*)d_out;
  float* ws  = (float*)d_ws;

  hipMemsetAsync(d_ws, 0, (WSBASE + (size_t)NSLICE * 13 * NN) * sizeof(float), stream);

  dim3 g1(NN / 256, BB, TT / TC);  // (8, 16, 16) = 2048 blocks
  stats_kernel<<<g1, 256, 0, stream>>>(pred, gt, vis, ws);
  final_kernel<<<1, 1024, 0, stream>>>(ws, out);
}